// Round 6
// baseline (377.035 us; speedup 1.0000x reference)
//
#include <hip/hip_runtime.h>

typedef __bf16 bf16_t;
typedef bf16_t bf16x8 __attribute__((ext_vector_type(8)));
typedef _Float16 f16_t;
typedef __fp16 hf16x2 __attribute__((ext_vector_type(2)));   // cvt_pkrtz return type
typedef f16_t f16x8 __attribute__((ext_vector_type(8)));
typedef float floatx4 __attribute__((ext_vector_type(4)));
typedef float floatx16 __attribute__((ext_vector_type(16)));

#define S_LEN 2048
#define DIM 768
#define NH 16
#define HD 48
#define HDP 64
#define BHEADS 64          // B * NH
#define ATT_SCALE 0.14433756729740643f  // 1/sqrt(48)
#define W_ELEMS (DIM * DIM)

typedef unsigned short u16;
typedef unsigned int u32;

__device__ __forceinline__ u16 f2b(float f) {
  union { float f; u32 i; } z; z.f = f;
  u32 i = z.i;
  return (u16)((i + 0x7fffu + ((i >> 16) & 1u)) >> 16);  // RNE
}
__device__ __forceinline__ u32 pack2(float a, float b) {
  return (u32)f2b(a) | ((u32)f2b(b) << 16);
}
__device__ __forceinline__ u32 pkrtz2(float a, float b) {   // 2x f32 -> packed f16
  union { hf16x2 h; u32 u; } z;
  z.h = __builtin_amdgcn_cvt_pkrtz(a, b);
  return z.u;
}
// v_permlane32_swap_b32: a' = [a.lanes0-31, b.lanes0-31]; b' = [a.lanes32-63, b.lanes32-63]
__device__ __forceinline__ void pl32swap(u32& a, u32& b) {
  asm("v_permlane32_swap_b32 %0, %1" : "+v"(a), "+v"(b));
}

// ---------------------------------------------------------------------------
// fp32 -> bf16 bulk convert, 8 floats/thread. Used for x (3072 blocks).
// ---------------------------------------------------------------------------
__global__ __launch_bounds__(256) void cvt_f32_bf16(
    const float* __restrict__ src, u16* __restrict__ dst)
{
  int idx = blockIdx.x * 256 + threadIdx.x;
  const float4* s = (const float4*)src;
  float4 a = s[idx * 2], b = s[idx * 2 + 1];
  *(uint4*)&dst[(size_t)idx * 8] =
      make_uint4(pack2(a.x, a.y), pack2(a.z, a.w), pack2(b.x, b.y), pack2(b.z, b.w));
}

// ---------------------------------------------------------------------------
// Convert the 4 weight matrices fp32 -> bf16 once per launch. grid (288, 4).
// ---------------------------------------------------------------------------
__global__ __launch_bounds__(256) void cvt_weights(
    const float* __restrict__ w0, const float* __restrict__ w1,
    const float* __restrict__ w2, const float* __restrict__ w3,
    u16* __restrict__ dst)
{
  const float* srcs[4] = {w0, w1, w2, w3};
  const float* src = srcs[blockIdx.y];
  u16* d = dst + (size_t)blockIdx.y * W_ELEMS;
  int idx = blockIdx.x * 256 + threadIdx.x;
  const float4* s = (const float4*)src;
  float4 a = s[idx * 2], b = s[idx * 2 + 1];
  *(uint4*)&d[(size_t)idx * 8] =
      make_uint4(pack2(a.x, a.y), pack2(a.z, a.w), pack2(b.x, b.y), pack2(b.z, b.w));
}

// ===========================================================================
// GEMM 128x128 tile, BK=32, 256 threads (4 waves, each 64x64 quadrant as 4x4
// 16x16x32 MFMA fragments). Double-buffered LDS, reg-staged issue-early /
// write-late (attn-proven T14 pattern), ONE barrier per K-step.
// LDS: 2 x (As 128x40 + Bs 128x40) u16 = 40960 B. T-overlay for V: 34816 B.
// ===========================================================================
#define AS(buf) ((u16(*)[40])(smem + (buf) * 10240))
#define BS(buf) ((u16(*)[40])(smem + (buf) * 10240 + 5120))

// ---------------------------------------------------------------------------
// Fused QKV: A = x_bf [8192][768]; Wbase = w_bf (Wq,Wk,Wv consecutive).
// grid 64*18 = 1152: bm = blk&63 (128 rows), bn = blk>>6 (0..17);
// mat = bn/6 (0=Q,1=K,2=V), n0 = (bn%6)*128.
// Q/K epilogue: bf16 head-scatter [bh][s][64] (Q scaled by ATT_SCALE).
// V epilogue:   f16 V^T [bh][d][s] via LDS transpose (T overlays staging).
// ---------------------------------------------------------------------------
__global__ __launch_bounds__(256, 2) void gemm_qkv(
    const u16* __restrict__ A, const u16* __restrict__ Wbase,
    const float* __restrict__ bq, const float* __restrict__ bk,
    const float* __restrict__ bv,
    u16* __restrict__ q_out, u16* __restrict__ k_out, u16* __restrict__ v_out)
{
  __shared__ __attribute__((aligned(16))) u16 smem[20480];

  const int tid = threadIdx.x;
  const int w = tid >> 6, lane = tid & 63, lo = lane & 15, quad = lane >> 4;
  const int wr = w >> 1, wc = w & 1;
  const int bm = blockIdx.x & 63, bn = blockIdx.x >> 6;
  const int mat = bn / 6;                 // 0=Q, 1=K, 2=V
  const int n0 = (bn - mat * 6) * 128;    // col offset within matrix
  const int m0 = bm * 128;
  const u16* W = Wbase + (size_t)mat * W_ELEMS;
  const float* bias = mat == 0 ? bq : (mat == 1 ? bk : bv);
  const float scale = mat == 0 ? ATT_SCALE : 1.0f;

  floatx4 acc[4][4];
#pragma unroll
  for (int mi = 0; mi < 4; mi++)
#pragma unroll
    for (int ni = 0; ni < 4; ni++) acc[mi][ni] = (floatx4){0.f, 0.f, 0.f, 0.f};

  uint4 ga[2], gb[2];
  // prologue: stage K-step 0 into buffer 0
#pragma unroll
  for (int it = 0; it < 2; ++it) {
    int c = tid + it * 256, r = c >> 2, cc = c & 3;
    ga[it] = *(const uint4*)&A[(size_t)(m0 + r) * DIM + cc * 8];
    gb[it] = *(const uint4*)&W[(size_t)(n0 + r) * DIM + cc * 8];
  }
#pragma unroll
  for (int it = 0; it < 2; ++it) {
    int c = tid + it * 256, r = c >> 2, cc = c & 3;
    *(uint4*)&AS(0)[r][cc * 8] = ga[it];
    *(uint4*)&BS(0)[r][cc * 8] = gb[it];
  }

  for (int ks = 0; ks < 24; ++ks) {
    const int cur = ks & 1;
    if (ks < 23) {
      const int kn = (ks + 1) * 32;
#pragma unroll
      for (int it = 0; it < 2; ++it) {
        int c = tid + it * 256, r = c >> 2, cc = c & 3;
        ga[it] = *(const uint4*)&A[(size_t)(m0 + r) * DIM + kn + cc * 8];
        gb[it] = *(const uint4*)&W[(size_t)(n0 + r) * DIM + kn + cc * 8];
      }
    }
    __syncthreads();
    bf16x8 af[4], bfr[4];
#pragma unroll
    for (int mi = 0; mi < 4; mi++) af[mi] = *(const bf16x8*)&AS(cur)[wr * 64 + mi * 16 + lo][quad * 8];
#pragma unroll
    for (int ni = 0; ni < 4; ni++) bfr[ni] = *(const bf16x8*)&BS(cur)[wc * 64 + ni * 16 + lo][quad * 8];
#pragma unroll
    for (int mi = 0; mi < 4; mi++)
#pragma unroll
      for (int ni = 0; ni < 4; ni++)
        acc[mi][ni] = __builtin_amdgcn_mfma_f32_16x16x32_bf16(af[mi], bfr[ni], acc[mi][ni], 0, 0, 0);
    if (ks < 23) {
      const int nb = cur ^ 1;
#pragma unroll
      for (int it = 0; it < 2; ++it) {
        int c = tid + it * 256, r = c >> 2, cc = c & 3;
        *(uint4*)&AS(nb)[r][cc * 8] = ga[it];
        *(uint4*)&BS(nb)[r][cc * 8] = gb[it];
      }
    }
  }

  if (mat < 2) {
    u16* out = mat == 0 ? q_out : k_out;
#pragma unroll
    for (int mi = 0; mi < 4; mi++)
#pragma unroll
      for (int ni = 0; ni < 4; ni++)
#pragma unroll
        for (int r = 0; r < 4; r++) {
          int row = m0 + wr * 64 + mi * 16 + quad * 4 + r;
          int col = n0 + wc * 64 + ni * 16 + lo;
          float v = (acc[mi][ni][r] + bias[col]) * scale;
          int b = row >> 11, s = row & 2047;
          int h = col / HD, d = col - h * HD;
          out[((size_t)((b * NH + h) * S_LEN + s)) * HDP + d] = f2b(v);
        }
  } else {
    __syncthreads();   // T overlays staging buffers still being read above
    u16 (*T)[136] = (u16(*)[136])smem;   // 128 x 136 u16 = 34816 B <= 40960
#pragma unroll
    for (int mi = 0; mi < 4; mi++)
#pragma unroll
      for (int ni = 0; ni < 4; ni++) {
        int col = wc * 64 + ni * 16 + lo;
        float bb = bias[n0 + col];
        float v0 = acc[mi][ni][0] + bb, v1 = acc[mi][ni][1] + bb;
        float v2 = acc[mi][ni][2] + bb, v3 = acc[mi][ni][3] + bb;
        *(uint2*)&T[col][wr * 64 + mi * 16 + quad * 4] =
            make_uint2(pkrtz2(v0, v1), pkrtz2(v2, v3));
      }
    __syncthreads();
    const int b = m0 >> 11, s0 = m0 & 2047;
#pragma unroll
    for (int it = 0; it < 8; ++it) {
      int ch = tid + it * 256;
      int col = ch >> 4, sc = ch & 15;
      int gcol = n0 + col;
      int h = gcol / HD, d = gcol - h * HD;
      size_t dst = ((size_t)(b * NH + h) * HDP + d) * S_LEN + s0 + sc * 8;
      *(uint4*)&v_out[dst] = *(const uint4*)&T[col][sc * 8];
    }
  }
}

// ---------------------------------------------------------------------------
// Wo GEMM: A = attn out, HEAD-MAJOR [bh][s][48] bf16; W = wo_bf; out fp32
// [8192][768]. grid 64*6 = 384. Same 128x128 pipelined structure.
// 8-col A chunks stay within one head (48 % 8 == 0), 16B-aligned (96 = 6*16).
// ---------------------------------------------------------------------------
__global__ __launch_bounds__(256, 2) void gemm_wo(
    const u16* __restrict__ A, const u16* __restrict__ W,
    const float* __restrict__ bias, float* __restrict__ out)
{
  __shared__ __attribute__((aligned(16))) u16 smem[20480];

  const int tid = threadIdx.x;
  const int w = tid >> 6, lane = tid & 63, lo = lane & 15, quad = lane >> 4;
  const int wr = w >> 1, wc = w & 1;
  const int bm = blockIdx.x & 63, bn = blockIdx.x >> 6;
  const int m0 = bm * 128, n0 = bn * 128;

  floatx4 acc[4][4];
#pragma unroll
  for (int mi = 0; mi < 4; mi++)
#pragma unroll
    for (int ni = 0; ni < 4; ni++) acc[mi][ni] = (floatx4){0.f, 0.f, 0.f, 0.f};

  uint4 ga[2], gb[2];
#pragma unroll
  for (int it = 0; it < 2; ++it) {
    int c = tid + it * 256, r = c >> 2, cc = c & 3;
    int c8 = cc * 8, h = c8 / HD, d = c8 - h * HD;
    int row = m0 + r, b = row >> 11, s = row & 2047;
    ga[it] = *(const uint4*)&A[((size_t)((b * NH + h) * S_LEN + s)) * HD + d];
    gb[it] = *(const uint4*)&W[(size_t)(n0 + r) * DIM + cc * 8];
  }
#pragma unroll
  for (int it = 0; it < 2; ++it) {
    int c = tid + it * 256, r = c >> 2, cc = c & 3;
    *(uint4*)&AS(0)[r][cc * 8] = ga[it];
    *(uint4*)&BS(0)[r][cc * 8] = gb[it];
  }

  for (int ks = 0; ks < 24; ++ks) {
    const int cur = ks & 1;
    if (ks < 23) {
      const int kn = (ks + 1) * 32;
#pragma unroll
      for (int it = 0; it < 2; ++it) {
        int c = tid + it * 256, r = c >> 2, cc = c & 3;
        int c8 = kn + cc * 8, h = c8 / HD, d = c8 - h * HD;
        int row = m0 + r, b = row >> 11, s = row & 2047;
        ga[it] = *(const uint4*)&A[((size_t)((b * NH + h) * S_LEN + s)) * HD + d];
        gb[it] = *(const uint4*)&W[(size_t)(n0 + r) * DIM + kn + cc * 8];
      }
    }
    __syncthreads();
    bf16x8 af[4], bfr[4];
#pragma unroll
    for (int mi = 0; mi < 4; mi++) af[mi] = *(const bf16x8*)&AS(cur)[wr * 64 + mi * 16 + lo][quad * 8];
#pragma unroll
    for (int ni = 0; ni < 4; ni++) bfr[ni] = *(const bf16x8*)&BS(cur)[wc * 64 + ni * 16 + lo][quad * 8];
#pragma unroll
    for (int mi = 0; mi < 4; mi++)
#pragma unroll
      for (int ni = 0; ni < 4; ni++)
        acc[mi][ni] = __builtin_amdgcn_mfma_f32_16x16x32_bf16(af[mi], bfr[ni], acc[mi][ni], 0, 0, 0);
    if (ks < 23) {
      const int nb = cur ^ 1;
#pragma unroll
      for (int it = 0; it < 2; ++it) {
        int c = tid + it * 256, r = c >> 2, cc = c & 3;
        *(uint4*)&AS(nb)[r][cc * 8] = ga[it];
        *(uint4*)&BS(nb)[r][cc * 8] = gb[it];
      }
    }
  }

#pragma unroll
  for (int mi = 0; mi < 4; mi++)
#pragma unroll
    for (int ni = 0; ni < 4; ni++)
#pragma unroll
      for (int r = 0; r < 4; r++) {
        int row = m0 + wr * 64 + mi * 16 + quad * 4 + r;
        int col = n0 + wc * 64 + ni * 16 + lo;
        out[(size_t)row * DIM + col] = acc[mi][ni][r] + bias[col];
      }
}

// ---------------------------------------------------------------------------
// Flash attention, 32x32x16 MFMA, swapped QK^T (mfma(K,Q) -> P[key][q=l31]).
// (unchanged from round 5: 105.9 us, FETCH 25.7MB, WRITE 18.4MB, verified)
// ---------------------------------------------------------------------------
#define STG_LOAD(k0n) do {                                                     \
  _Pragma("unroll")                                                            \
  for (int it = 0; it < 3; ++it) {                                             \
    int c = tid + it * 256;                                                    \
    if (c < 384) {                                                             \
      int r = c / 6, cc = c - r * 6;                                           \
      stg[it] = *(const uint4*)&K[base + (size_t)((k0n) + r) * HDP + cc * 8];  \
    } else {                                                                   \
      int c2 = c - 384, r = c2 >> 3, cc = c2 & 7;                              \
      stg[it] = *(const uint4*)&V[base + (size_t)r * S_LEN + (k0n) + cc * 8];  \
    }                                                                          \
  }                                                                            \
} while (0)

#define STG_WRITE(bufi) do {                                                   \
  _Pragma("unroll")                                                            \
  for (int it = 0; it < 3; ++it) {                                             \
    int c = tid + it * 256;                                                    \
    if (c < 384) {                                                             \
      int r = c / 6, cc = c - r * 6;                                           \
      *(uint4*)&Ks[bufi][r][cc * 8] = stg[it];                                 \
    } else {                                                                   \
      int c2 = c - 384, r = c2 >> 3, cc = c2 & 7;                              \
      *(uint4*)&Vt[bufi][r][cc * 8] = stg[it];                                 \
    }                                                                          \
  }                                                                            \
} while (0)

__global__ __launch_bounds__(256, 2) void attn_kernel(
    const u16* __restrict__ Q, const u16* __restrict__ K,
    const u16* __restrict__ V, u16* __restrict__ O)
{
  __shared__ __attribute__((aligned(16))) u16 Ks[2][64][56];  // keys x d(<48)
  __shared__ __attribute__((aligned(16))) u16 Vt[2][64][72];  // d x keys (f16)

  const int tid = threadIdx.x;
  const int w = tid >> 6, lane = tid & 63, l31 = lane & 31, hi = lane >> 5;
  // XCD-locality swizzle: 512 flat blocks; all 8 q-blocks of a bh and 8
  // consecutive bh share one XCD (id%8 = XCD round-robin assumption).
  const int flat = blockIdx.x;
  const int xcd = flat & 7, sub = flat >> 3;          // sub in [0,64)
  const int bh = xcd * 8 + (sub >> 3);                // 8 bh per XCD
  const int q0 = (sub & 7) * 256;                     // 8 q-blocks per bh
  const size_t base = (size_t)bh * S_LEN * HDP;

  // Q fragments (B-operand of swapped QK): Q[q0+w*64+t*32+l31][ks*16+hi*8+j]
  bf16x8 qf[2][3];
#pragma unroll
  for (int t = 0; t < 2; t++)
#pragma unroll
    for (int ks = 0; ks < 3; ks++)
      qf[t][ks] = *(const bf16x8*)
          &Q[base + (size_t)(q0 + w * 64 + t * 32 + l31) * HDP + ks * 16 + hi * 8];

  floatx16 oacc[2][2];
#pragma unroll
  for (int t = 0; t < 2; t++)
#pragma unroll
    for (int nd = 0; nd < 2; nd++)
#pragma unroll
      for (int r = 0; r < 16; r++) oacc[t][nd][r] = 0.f;

  float l_lane[2] = {0.f, 0.f};   // f32 denom for q = l31 (this lane's key half)

  uint4 stg[3];
  STG_LOAD(0);
  STG_WRITE(0);

  for (int ti = 0; ti < 32; ++ti) {
    const int cur = ti & 1;
    if (ti < 31) STG_LOAD((ti + 1) * 64);   // in flight across the barrier (T14)
    __syncthreads();

    // K A-fragments, shared by both q-subtiles
    bf16x8 ak[2][3];
#pragma unroll
    for (int na = 0; na < 2; na++)
#pragma unroll
      for (int ks = 0; ks < 3; ks++)
        ak[na][ks] = *(const bf16x8*)&Ks[cur][na * 32 + l31][ks * 16 + hi * 8];

    // QK^T (swapped) + exp + pack; pk[t][na][m] covers keys
    // na*32 + 8*(m>>1) + 4*hi + 2*(m&1) + {0,1}, all for q = l31.
    u32 pk[2][2][8];
#pragma unroll
    for (int t = 0; t < 2; t++) {
      floatx16 s0, s1;
#pragma unroll
      for (int r = 0; r < 16; r++) { s0[r] = 0.f; s1[r] = 0.f; }
#pragma unroll
      for (int ks = 0; ks < 3; ks++) {
        s0 = __builtin_amdgcn_mfma_f32_32x32x16_bf16(ak[0][ks], qf[t][ks], s0, 0, 0, 0);
        s1 = __builtin_amdgcn_mfma_f32_32x32x16_bf16(ak[1][ks], qf[t][ks], s1, 0, 0, 0);
      }
#pragma unroll
      for (int m = 0; m < 8; m++) {
        float a0 = __expf(s0[2 * m]), a1 = __expf(s0[2 * m + 1]);
        float b0 = __expf(s1[2 * m]), b1 = __expf(s1[2 * m + 1]);
        l_lane[t] += (a0 + a1) + (b0 + b1);
        pk[t][0][m] = pkrtz2(a0, a1);
        pk[t][1][m] = pkrtz2(b0, b1);
      }
    }

    // O += P @ V : A-frag rebuilt in registers via permlane32_swap
#pragma unroll
    for (int kt = 0; kt < 4; kt++) {
      f16x8 bv0 = *(const f16x8*)&Vt[cur][l31][kt * 16 + hi * 8];
      f16x8 bv1 = *(const f16x8*)&Vt[cur][32 + l31][kt * 16 + hi * 8];
      const int na = kt >> 1, k4 = (kt & 1) * 4;
#pragma unroll
      for (int t = 0; t < 2; t++) {
        u32 w0 = pk[t][na][k4 + 0], w2 = pk[t][na][k4 + 2];
        u32 w1 = pk[t][na][k4 + 1], w3 = pk[t][na][k4 + 3];
        pl32swap(w0, w2);
        pl32swap(w1, w3);
        union { u32 u[4]; f16x8 f; } af;
        af.u[0] = w0; af.u[1] = w1; af.u[2] = w2; af.u[3] = w3;
        oacc[t][0] = __builtin_amdgcn_mfma_f32_32x32x16_f16(af.f, bv0, oacc[t][0], 0, 0, 0);
        oacc[t][1] = __builtin_amdgcn_mfma_f32_32x32x16_f16(af.f, bv1, oacc[t][1], 0, 0, 0);
      }
    }

    if (ti < 31) STG_WRITE(cur ^ 1);   // write-late into the other buffer
  }

  // epilogue: complete l(q=l31) across halves, fetch per-output-row denom via
  // __shfl from lane q_local, write HEAD-MAJOR O[bh][q][48] (contiguous 96B
  // rows, block-private -> full-line writes on one XCD).
  const size_t obase = (size_t)bh * S_LEN * HD;
  float lt_full[2];
#pragma unroll
  for (int t = 0; t < 2; t++)
    lt_full[t] = l_lane[t] + __shfl_xor(l_lane[t], 32);
#pragma unroll
  for (int t = 0; t < 2; t++) {
#pragma unroll
    for (int r = 0; r < 16; r++) {
      int q_local = (r & 3) + 8 * (r >> 2) + 4 * hi;
      float l_r = __shfl(lt_full[t], q_local);
      float inv = 1.f / l_r;
      int q = q0 + w * 64 + t * 32 + q_local;
      u16* orow = O + obase + (size_t)q * HD;
      orow[l31] = f2b(oacc[t][0][r] * inv);
      if (l31 < 16) orow[32 + l31] = f2b(oacc[t][1][r] * inv);
    }
  }
}

// ---------------------------------------------------------------------------
extern "C" void kernel_launch(void* const* d_in, const int* in_sizes, int n_in,
                              void* d_out, int out_size, void* d_ws, size_t ws_size,
                              hipStream_t stream)
{
  const float* x  = (const float*)d_in[0];
  const float* Wq = (const float*)d_in[1];
  const float* bq = (const float*)d_in[2];
  const float* Wk = (const float*)d_in[3];
  const float* bk = (const float*)d_in[4];
  const float* Wv = (const float*)d_in[5];
  const float* bv = (const float*)d_in[6];
  const float* Wo = (const float*)d_in[7];
  const float* bo = (const float*)d_in[8];

  u16* ws   = (u16*)d_ws;
  const size_t qkv_elems = (size_t)BHEADS * S_LEN * HDP;  // 8.39M u16 each
  u16* q_ws = ws;                                         // [bh][s][64] bf16
  u16* k_ws = q_ws + qkv_elems;                           // [bh][s][64] bf16
  u16* v_ws = k_ws + qkv_elems;                           // [bh][d][s]  f16 (V^T)
  u16* x_bf = v_ws + qkv_elems;                           // [8192][768] bf16
  u16* a_ws = x_bf;   // aliased: attn writes [bh][s][48] (6.29M u16 = x_bf size)
  u16* w_bf = x_bf + (size_t)8192 * DIM;                  // 4x[768][768] bf16

  cvt_f32_bf16<<<dim3(3072), dim3(256), 0, stream>>>(x, x_bf);
  cvt_weights<<<dim3(288, 4), dim3(256), 0, stream>>>(Wq, Wk, Wv, Wo, w_bf);
  u16* wo_bf = w_bf + (size_t)3 * W_ELEMS;

  gemm_qkv<<<dim3(1152), dim3(256), 0, stream>>>(x_bf, w_bf, bq, bk, bv,
                                                 q_ws, k_ws, v_ws);
  attn_kernel<<<dim3(512), dim3(256), 0, stream>>>(q_ws, k_ws, v_ws, a_ws);
  gemm_wo<<<dim3(384), dim3(256), 0, stream>>>(a_ws, wo_bf, bo, (float*)d_out);
}

// Round 7
// 265.310 us; speedup vs baseline: 1.4211x; 1.4211x over previous
//
#include <hip/hip_runtime.h>

typedef __bf16 bf16_t;
typedef bf16_t bf16x8 __attribute__((ext_vector_type(8)));
typedef _Float16 f16_t;
typedef __fp16 hf16x2 __attribute__((ext_vector_type(2)));   // cvt_pkrtz return type
typedef f16_t f16x8 __attribute__((ext_vector_type(8)));
typedef float floatx4 __attribute__((ext_vector_type(4)));
typedef float floatx16 __attribute__((ext_vector_type(16)));

#define S_LEN 2048
#define DIM 768
#define NH 16
#define HD 48
#define HDP 64
#define BHEADS 64          // B * NH
#define ATT_SCALE 0.14433756729740643f  // 1/sqrt(48)
#define W_ELEMS (DIM * DIM)

typedef unsigned short u16;
typedef unsigned int u32;

__device__ __forceinline__ u16 f2b(float f) {
  union { float f; u32 i; } z; z.f = f;
  u32 i = z.i;
  return (u16)((i + 0x7fffu + ((i >> 16) & 1u)) >> 16);  // RNE
}
__device__ __forceinline__ u32 pack2(float a, float b) {
  return (u32)f2b(a) | ((u32)f2b(b) << 16);
}
__device__ __forceinline__ u32 pkrtz2(float a, float b) {   // 2x f32 -> packed f16
  union { hf16x2 h; u32 u; } z;
  z.h = __builtin_amdgcn_cvt_pkrtz(a, b);
  return z.u;
}
// v_permlane32_swap_b32: a' = [a.lanes0-31, b.lanes0-31]; b' = [a.lanes32-63, b.lanes32-63]
__device__ __forceinline__ void pl32swap(u32& a, u32& b) {
  asm("v_permlane32_swap_b32 %0, %1" : "+v"(a), "+v"(b));
}

// ---------------------------------------------------------------------------
// Fused fp32 -> bf16 convert for x (blocks 0..3071) and the 4 weight
// matrices (blocks 3072..4223, 288 per matrix). One launch instead of two.
// ---------------------------------------------------------------------------
__global__ __launch_bounds__(256) void cvt_all(
    const float* __restrict__ x,
    const float* __restrict__ w0, const float* __restrict__ w1,
    const float* __restrict__ w2, const float* __restrict__ w3,
    u16* __restrict__ x_dst, u16* __restrict__ w_dst)
{
  const int blk = blockIdx.x;
  const float* src;
  u16* dst;
  int idx;
  if (blk < 3072) {
    src = x; dst = x_dst; idx = blk * 256 + threadIdx.x;
  } else {
    int wb = blk - 3072;
    int j = wb / 288;
    src = (j == 0) ? w0 : (j == 1) ? w1 : (j == 2) ? w2 : w3;
    dst = w_dst + (size_t)j * W_ELEMS;
    idx = (wb - j * 288) * 256 + threadIdx.x;
  }
  const float4* s = (const float4*)src;
  float4 a = s[idx * 2], b = s[idx * 2 + 1];
  *(uint4*)&dst[(size_t)idx * 8] =
      make_uint4(pack2(a.x, a.y), pack2(a.z, a.w), pack2(b.x, b.y), pack2(b.z, b.w));
}

// ---------------------------------------------------------------------------
// Fused QKV GEMM: C = (x_bf @ W^T + bias) * scale, round-5 verified structure
// (tile 128x64, BK=32, 256 threads, 2 barriers/K-step, direct LDS staging).
// grid 2304 = 64 m-blocks x 36 n-blocks; mat = bn/12 (0=Q,1=K,2=V), uniform
// per block. Q/K epilogue: bf16 head-scatter [bh][s][64] (Q scaled); V:
// f16 V^T [bh][d][s] via LDS-transpose.
// ---------------------------------------------------------------------------
__global__ __launch_bounds__(256) void gemm_qkv(
    const u16* __restrict__ A, const u16* __restrict__ Wbase,
    const float* __restrict__ bq, const float* __restrict__ bk,
    const float* __restrict__ bv,
    u16* __restrict__ q_out, u16* __restrict__ k_out, u16* __restrict__ v_out)
{
  // As: 128x40 (5120), Bs: 64x40 (2560); T (V): 64x136 u16 (8704)
  __shared__ __attribute__((aligned(16))) u16 smem[8704];
  u16 (*As)[40] = (u16(*)[40])smem;
  u16 (*Bs)[40] = (u16(*)[40])(smem + 5120);

  const int tid = threadIdx.x;
  const int w = tid >> 6, lane = tid & 63, lo = lane & 15, quad = lane >> 4;
  const int bm = blockIdx.x & 63, bn = blockIdx.x >> 6;
  const int mat = bn / 12;                 // 0=Q, 1=K, 2=V
  const int n0 = (bn - mat * 12) * 64;     // col offset within matrix
  const int m0 = bm * 128;
  const u16* W = Wbase + (size_t)mat * W_ELEMS;
  const float* bias = mat == 0 ? bq : (mat == 1 ? bk : bv);
  const float scale = mat == 0 ? ATT_SCALE : 1.0f;

  floatx4 acc[2][4];
#pragma unroll
  for (int mi = 0; mi < 2; mi++)
#pragma unroll
    for (int ni = 0; ni < 4; ni++) acc[mi][ni] = (floatx4){0.f, 0.f, 0.f, 0.f};

  for (int k0 = 0; k0 < DIM; k0 += 32) {
    // A tile 128x32: 512 chunks, 2/thread
#pragma unroll
    for (int it = 0; it < 2; ++it) {
      int c = tid + it * 256;
      int r = c >> 2, cc = c & 3;
      *(uint4*)&As[r][cc * 8] = *(const uint4*)&A[(size_t)(m0 + r) * DIM + k0 + cc * 8];
    }
    // W tile 64x32: 256 chunks, 1/thread
    {
      int r = tid >> 2, cc = tid & 3;
      *(uint4*)&Bs[r][cc * 8] = *(const uint4*)&W[(size_t)(n0 + r) * DIM + k0 + cc * 8];
    }
    __syncthreads();
    bf16x8 af[2], bfr[4];
#pragma unroll
    for (int mi = 0; mi < 2; mi++) af[mi] = *(const bf16x8*)&As[w * 32 + mi * 16 + lo][quad * 8];
#pragma unroll
    for (int ni = 0; ni < 4; ni++) bfr[ni] = *(const bf16x8*)&Bs[ni * 16 + lo][quad * 8];
#pragma unroll
    for (int mi = 0; mi < 2; mi++)
#pragma unroll
      for (int ni = 0; ni < 4; ni++)
        acc[mi][ni] = __builtin_amdgcn_mfma_f32_16x16x32_bf16(af[mi], bfr[ni], acc[mi][ni], 0, 0, 0);
    __syncthreads();
  }

  if (mat == 2) {
    u16 (*T)[136] = (u16(*)[136])smem;
#pragma unroll
    for (int mi = 0; mi < 2; mi++)
#pragma unroll
      for (int ni = 0; ni < 4; ni++) {
        int col = ni * 16 + lo;
        float bb = bias[n0 + col];
        float v0 = acc[mi][ni][0] + bb, v1 = acc[mi][ni][1] + bb;
        float v2 = acc[mi][ni][2] + bb, v3 = acc[mi][ni][3] + bb;
        *(uint2*)&T[col][w * 32 + mi * 16 + quad * 4] =
            make_uint2(pkrtz2(v0, v1), pkrtz2(v2, v3));
      }
    __syncthreads();
    const int b = m0 >> 11, s0 = m0 & 2047;
#pragma unroll
    for (int it = 0; it < 4; ++it) {
      int ch = tid + it * 256;
      int col = ch >> 4, sc = ch & 15;
      int gcol = n0 + col;
      int h = gcol / HD, d = gcol - h * HD;
      size_t dst = ((size_t)(b * NH + h) * HDP + d) * S_LEN + s0 + sc * 8;
      *(uint4*)&v_out[dst] = *(const uint4*)&T[col][sc * 8];
    }
    return;
  }

  u16* out = mat == 0 ? q_out : k_out;
#pragma unroll
  for (int mi = 0; mi < 2; mi++)
#pragma unroll
    for (int ni = 0; ni < 4; ni++)
#pragma unroll
      for (int r = 0; r < 4; r++) {
        int row = m0 + w * 32 + mi * 16 + quad * 4 + r;
        int col = n0 + ni * 16 + lo;
        float v = (acc[mi][ni][r] + bias[col]) * scale;
        int b = row >> 11, s = row & 2047;
        int h = col / HD, d = col - h * HD;
        out[((size_t)((b * NH + h) * S_LEN + s)) * HDP + d] = f2b(v);
      }
}

// ---------------------------------------------------------------------------
// Wo GEMM (round-5 verified): A = attn out HEAD-MAJOR [bh][s][48] bf16;
// out fp32 [8192][768]. Tile 128x64, grid 768. 8-col A chunks stay within
// one head (48 % 8 == 0), 16B-aligned (96 = 6*16).
// ---------------------------------------------------------------------------
__global__ __launch_bounds__(256) void gemm_wo(
    const u16* __restrict__ A, const u16* __restrict__ W,
    const float* __restrict__ bias, float* __restrict__ out)
{
  __shared__ __attribute__((aligned(16))) u16 smem[8704];
  u16 (*As)[40] = (u16(*)[40])smem;
  u16 (*Bs)[40] = (u16(*)[40])(smem + 5120);

  const int tid = threadIdx.x;
  const int w = tid >> 6, lane = tid & 63, lo = lane & 15, quad = lane >> 4;
  const int bm = blockIdx.x & 63, bn = blockIdx.x >> 6;
  const int m0 = bm * 128, n0 = bn * 64;

  floatx4 acc[2][4];
#pragma unroll
  for (int mi = 0; mi < 2; mi++)
#pragma unroll
    for (int ni = 0; ni < 4; ni++) acc[mi][ni] = (floatx4){0.f, 0.f, 0.f, 0.f};

  for (int k0 = 0; k0 < DIM; k0 += 32) {
#pragma unroll
    for (int it = 0; it < 2; ++it) {
      int c = tid + it * 256;
      int r = c >> 2, cc = c & 3;
      int row = m0 + r, c8 = k0 + cc * 8;
      int h = c8 / HD, d = c8 - h * HD;
      int b = row >> 11, s = row & 2047;
      *(uint4*)&As[r][cc * 8] =
          *(const uint4*)&A[((size_t)((b * NH + h) * S_LEN + s)) * HD + d];
    }
    {
      int r = tid >> 2, cc = tid & 3;
      *(uint4*)&Bs[r][cc * 8] = *(const uint4*)&W[(size_t)(n0 + r) * DIM + k0 + cc * 8];
    }
    __syncthreads();
    bf16x8 af[2], bfr[4];
#pragma unroll
    for (int mi = 0; mi < 2; mi++) af[mi] = *(const bf16x8*)&As[w * 32 + mi * 16 + lo][quad * 8];
#pragma unroll
    for (int ni = 0; ni < 4; ni++) bfr[ni] = *(const bf16x8*)&Bs[ni * 16 + lo][quad * 8];
#pragma unroll
    for (int mi = 0; mi < 2; mi++)
#pragma unroll
      for (int ni = 0; ni < 4; ni++)
        acc[mi][ni] = __builtin_amdgcn_mfma_f32_16x16x32_bf16(af[mi], bfr[ni], acc[mi][ni], 0, 0, 0);
    __syncthreads();
  }

#pragma unroll
  for (int mi = 0; mi < 2; mi++)
#pragma unroll
    for (int ni = 0; ni < 4; ni++)
#pragma unroll
      for (int r = 0; r < 4; r++) {
        int row = m0 + w * 32 + mi * 16 + quad * 4 + r;
        int col = n0 + ni * 16 + lo;
        out[(size_t)row * DIM + col] = acc[mi][ni][r] + bias[col];
      }
}

// ---------------------------------------------------------------------------
// Flash attention, 32x32x16 MFMA, swapped QK^T (mfma(K,Q) -> P[key][q=l31]).
// (unchanged from round 5: 105.9 us, FETCH 25.7MB, WRITE 18.4MB, verified)
// ---------------------------------------------------------------------------
#define STG_LOAD(k0n) do {                                                     \
  _Pragma("unroll")                                                            \
  for (int it = 0; it < 3; ++it) {                                             \
    int c = tid + it * 256;                                                    \
    if (c < 384) {                                                             \
      int r = c / 6, cc = c - r * 6;                                           \
      stg[it] = *(const uint4*)&K[base + (size_t)((k0n) + r) * HDP + cc * 8];  \
    } else {                                                                   \
      int c2 = c - 384, r = c2 >> 3, cc = c2 & 7;                              \
      stg[it] = *(const uint4*)&V[base + (size_t)r * S_LEN + (k0n) + cc * 8];  \
    }                                                                          \
  }                                                                            \
} while (0)

#define STG_WRITE(bufi) do {                                                   \
  _Pragma("unroll")                                                            \
  for (int it = 0; it < 3; ++it) {                                             \
    int c = tid + it * 256;                                                    \
    if (c < 384) {                                                             \
      int r = c / 6, cc = c - r * 6;                                           \
      *(uint4*)&Ks[bufi][r][cc * 8] = stg[it];                                 \
    } else {                                                                   \
      int c2 = c - 384, r = c2 >> 3, cc = c2 & 7;                              \
      *(uint4*)&Vt[bufi][r][cc * 8] = stg[it];                                 \
    }                                                                          \
  }                                                                            \
} while (0)

__global__ __launch_bounds__(256, 2) void attn_kernel(
    const u16* __restrict__ Q, const u16* __restrict__ K,
    const u16* __restrict__ V, u16* __restrict__ O)
{
  __shared__ __attribute__((aligned(16))) u16 Ks[2][64][56];  // keys x d(<48)
  __shared__ __attribute__((aligned(16))) u16 Vt[2][64][72];  // d x keys (f16)

  const int tid = threadIdx.x;
  const int w = tid >> 6, lane = tid & 63, l31 = lane & 31, hi = lane >> 5;
  // XCD-locality swizzle: 512 flat blocks; all 8 q-blocks of a bh and 8
  // consecutive bh share one XCD (id%8 = XCD round-robin assumption).
  const int flat = blockIdx.x;
  const int xcd = flat & 7, sub = flat >> 3;          // sub in [0,64)
  const int bh = xcd * 8 + (sub >> 3);                // 8 bh per XCD
  const int q0 = (sub & 7) * 256;                     // 8 q-blocks per bh
  const size_t base = (size_t)bh * S_LEN * HDP;

  // Q fragments (B-operand of swapped QK): Q[q0+w*64+t*32+l31][ks*16+hi*8+j]
  bf16x8 qf[2][3];
#pragma unroll
  for (int t = 0; t < 2; t++)
#pragma unroll
    for (int ks = 0; ks < 3; ks++)
      qf[t][ks] = *(const bf16x8*)
          &Q[base + (size_t)(q0 + w * 64 + t * 32 + l31) * HDP + ks * 16 + hi * 8];

  floatx16 oacc[2][2];
#pragma unroll
  for (int t = 0; t < 2; t++)
#pragma unroll
    for (int nd = 0; nd < 2; nd++)
#pragma unroll
      for (int r = 0; r < 16; r++) oacc[t][nd][r] = 0.f;

  float l_lane[2] = {0.f, 0.f};   // f32 denom for q = l31 (this lane's key half)

  uint4 stg[3];
  STG_LOAD(0);
  STG_WRITE(0);

  for (int ti = 0; ti < 32; ++ti) {
    const int cur = ti & 1;
    if (ti < 31) STG_LOAD((ti + 1) * 64);   // in flight across the barrier (T14)
    __syncthreads();

    // K A-fragments, shared by both q-subtiles
    bf16x8 ak[2][3];
#pragma unroll
    for (int na = 0; na < 2; na++)
#pragma unroll
      for (int ks = 0; ks < 3; ks++)
        ak[na][ks] = *(const bf16x8*)&Ks[cur][na * 32 + l31][ks * 16 + hi * 8];

    // QK^T (swapped) + exp + pack; pk[t][na][m] covers keys
    // na*32 + 8*(m>>1) + 4*hi + 2*(m&1) + {0,1}, all for q = l31.
    u32 pk[2][2][8];
#pragma unroll
    for (int t = 0; t < 2; t++) {
      floatx16 s0, s1;
#pragma unroll
      for (int r = 0; r < 16; r++) { s0[r] = 0.f; s1[r] = 0.f; }
#pragma unroll
      for (int ks = 0; ks < 3; ks++) {
        s0 = __builtin_amdgcn_mfma_f32_32x32x16_bf16(ak[0][ks], qf[t][ks], s0, 0, 0, 0);
        s1 = __builtin_amdgcn_mfma_f32_32x32x16_bf16(ak[1][ks], qf[t][ks], s1, 0, 0, 0);
      }
#pragma unroll
      for (int m = 0; m < 8; m++) {
        float a0 = __expf(s0[2 * m]), a1 = __expf(s0[2 * m + 1]);
        float b0 = __expf(s1[2 * m]), b1 = __expf(s1[2 * m + 1]);
        l_lane[t] += (a0 + a1) + (b0 + b1);
        pk[t][0][m] = pkrtz2(a0, a1);
        pk[t][1][m] = pkrtz2(b0, b1);
      }
    }

    // O += P @ V : A-frag rebuilt in registers via permlane32_swap
#pragma unroll
    for (int kt = 0; kt < 4; kt++) {
      f16x8 bv0 = *(const f16x8*)&Vt[cur][l31][kt * 16 + hi * 8];
      f16x8 bv1 = *(const f16x8*)&Vt[cur][32 + l31][kt * 16 + hi * 8];
      const int na = kt >> 1, k4 = (kt & 1) * 4;
#pragma unroll
      for (int t = 0; t < 2; t++) {
        u32 w0 = pk[t][na][k4 + 0], w2 = pk[t][na][k4 + 2];
        u32 w1 = pk[t][na][k4 + 1], w3 = pk[t][na][k4 + 3];
        pl32swap(w0, w2);
        pl32swap(w1, w3);
        union { u32 u[4]; f16x8 f; } af;
        af.u[0] = w0; af.u[1] = w1; af.u[2] = w2; af.u[3] = w3;
        oacc[t][0] = __builtin_amdgcn_mfma_f32_32x32x16_f16(af.f, bv0, oacc[t][0], 0, 0, 0);
        oacc[t][1] = __builtin_amdgcn_mfma_f32_32x32x16_f16(af.f, bv1, oacc[t][1], 0, 0, 0);
      }
    }

    if (ti < 31) STG_WRITE(cur ^ 1);   // write-late into the other buffer
  }

  // epilogue: complete l(q=l31) across halves, fetch per-output-row denom via
  // __shfl from lane q_local, write HEAD-MAJOR O[bh][q][48] (contiguous 96B
  // rows, block-private -> full-line writes on one XCD).
  const size_t obase = (size_t)bh * S_LEN * HD;
  float lt_full[2];
#pragma unroll
  for (int t = 0; t < 2; t++)
    lt_full[t] = l_lane[t] + __shfl_xor(l_lane[t], 32);
#pragma unroll
  for (int t = 0; t < 2; t++) {
#pragma unroll
    for (int r = 0; r < 16; r++) {
      int q_local = (r & 3) + 8 * (r >> 2) + 4 * hi;
      float l_r = __shfl(lt_full[t], q_local);
      float inv = 1.f / l_r;
      int q = q0 + w * 64 + t * 32 + q_local;
      u16* orow = O + obase + (size_t)q * HD;
      orow[l31] = f2b(oacc[t][0][r] * inv);
      if (l31 < 16) orow[32 + l31] = f2b(oacc[t][1][r] * inv);
    }
  }
}

// ---------------------------------------------------------------------------
extern "C" void kernel_launch(void* const* d_in, const int* in_sizes, int n_in,
                              void* d_out, int out_size, void* d_ws, size_t ws_size,
                              hipStream_t stream)
{
  const float* x  = (const float*)d_in[0];
  const float* Wq = (const float*)d_in[1];
  const float* bq = (const float*)d_in[2];
  const float* Wk = (const float*)d_in[3];
  const float* bk = (const float*)d_in[4];
  const float* Wv = (const float*)d_in[5];
  const float* bv = (const float*)d_in[6];
  const float* Wo = (const float*)d_in[7];
  const float* bo = (const float*)d_in[8];

  u16* ws   = (u16*)d_ws;
  const size_t qkv_elems = (size_t)BHEADS * S_LEN * HDP;  // 8.39M u16 each
  u16* q_ws = ws;                                         // [bh][s][64] bf16
  u16* k_ws = q_ws + qkv_elems;                           // [bh][s][64] bf16
  u16* v_ws = k_ws + qkv_elems;                           // [bh][d][s]  f16 (V^T)
  u16* x_bf = v_ws + qkv_elems;                           // [8192][768] bf16
  u16* a_ws = x_bf;   // aliased: attn writes [bh][s][48] (6.29M u16 = x_bf size)
  u16* w_bf = x_bf + (size_t)8192 * DIM;                  // 4x[768][768] bf16
  u16* wo_bf = w_bf + (size_t)3 * W_ELEMS;

  cvt_all<<<dim3(4224), dim3(256), 0, stream>>>(x, Wq, Wk, Wv, Wo, x_bf, w_bf);
  gemm_qkv<<<dim3(2304), dim3(256), 0, stream>>>(x_bf, w_bf, bq, bk, bv,
                                                 q_ws, k_ws, v_ws);
  attn_kernel<<<dim3(512), dim3(256), 0, stream>>>(q_ws, k_ws, v_ws, a_ws);
  gemm_wo<<<dim3(768), dim3(256), 0, stream>>>(a_ws, wo_bf, bo, (float*)d_out);
}

// Round 8
// 264.284 us; speedup vs baseline: 1.4266x; 1.0039x over previous
//
#include <hip/hip_runtime.h>

typedef __bf16 bf16_t;
typedef bf16_t bf16x8 __attribute__((ext_vector_type(8)));
typedef _Float16 f16_t;
typedef __fp16 hf16x2 __attribute__((ext_vector_type(2)));   // cvt_pkrtz return type
typedef f16_t f16x8 __attribute__((ext_vector_type(8)));
typedef float floatx4 __attribute__((ext_vector_type(4)));
typedef float floatx16 __attribute__((ext_vector_type(16)));

#define S_LEN 2048
#define DIM 768
#define NH 16
#define HD 48
#define HDP 64
#define BHEADS 64          // B * NH
#define ATT_SCALE 0.14433756729740643f  // 1/sqrt(48)
#define W_ELEMS (DIM * DIM)

typedef unsigned short u16;
typedef unsigned int u32;

__device__ __forceinline__ u16 f2b(float f) {
  union { float f; u32 i; } z; z.f = f;
  u32 i = z.i;
  return (u16)((i + 0x7fffu + ((i >> 16) & 1u)) >> 16);  // RNE
}
__device__ __forceinline__ u32 pack2(float a, float b) {
  return (u32)f2b(a) | ((u32)f2b(b) << 16);
}
__device__ __forceinline__ u32 pkrtz2(float a, float b) {   // 2x f32 -> packed f16
  union { hf16x2 h; u32 u; } z;
  z.h = __builtin_amdgcn_cvt_pkrtz(a, b);
  return z.u;
}
// v_permlane32_swap_b32: a' = [a.lanes0-31, b.lanes0-31]; b' = [a.lanes32-63, b.lanes32-63]
__device__ __forceinline__ void pl32swap(u32& a, u32& b) {
  asm("v_permlane32_swap_b32 %0, %1" : "+v"(a), "+v"(b));
}
// async global->LDS DMA, 16B per lane. LDS dest is wave-uniform base + lane*16;
// global src is per-lane. vmcnt-counted; __syncthreads() drains it.
__device__ __forceinline__ void gld_lds16(const void* g, void* l) {
  __builtin_amdgcn_global_load_lds(
      (const __attribute__((address_space(1))) u32*)g,
      (__attribute__((address_space(3))) u32*)l, 16, 0, 0);
}

// ---------------------------------------------------------------------------
// Fused fp32 -> bf16 convert for x (blocks 0..3071) and the 4 weight
// matrices (blocks 3072..4223, 288 per matrix). One launch instead of two.
// ---------------------------------------------------------------------------
__global__ __launch_bounds__(256) void cvt_all(
    const float* __restrict__ x,
    const float* __restrict__ w0, const float* __restrict__ w1,
    const float* __restrict__ w2, const float* __restrict__ w3,
    u16* __restrict__ x_dst, u16* __restrict__ w_dst)
{
  const int blk = blockIdx.x;
  const float* src;
  u16* dst;
  int idx;
  if (blk < 3072) {
    src = x; dst = x_dst; idx = blk * 256 + threadIdx.x;
  } else {
    int wb = blk - 3072;
    int j = wb / 288;
    src = (j == 0) ? w0 : (j == 1) ? w1 : (j == 2) ? w2 : w3;
    dst = w_dst + (size_t)j * W_ELEMS;
    idx = (wb - j * 288) * 256 + threadIdx.x;
  }
  const float4* s = (const float4*)src;
  float4 a = s[idx * 2], b = s[idx * 2 + 1];
  *(uint4*)&dst[(size_t)idx * 8] =
      make_uint4(pack2(a.x, a.y), pack2(a.z, a.w), pack2(b.x, b.y), pack2(b.z, b.w));
}

// ===========================================================================
// GEMM staging via global_load_lds (m97 rung): LINEAR LDS (pitch 32 u16),
// source-side column XOR swizzle ccg = ccl ^ ((r>>1)&3) with the SAME XOR on
// the read side (rule 21: linear dest + inverse-swz source + swz read) ->
// reads spread over 8 bank-groups x 2 lanes = conflict-free; global
// coalescing preserved (XOR permutes lanes within one 64B line).
// Tile 128x64, BK=32, 2 barriers/K-step, epilogues unchanged from round 7.
// LDS: As 128x32 + Bs 64x32 = 6144 u16; T overlay (V) 64x136 = 8704 u16.
// ===========================================================================

// ---------------------------------------------------------------------------
// Fused QKV GEMM: C = (x_bf @ W^T + bias) * scale. grid 2304 = 64 x 36;
// mat = bn/12 (0=Q,1=K,2=V). Q/K: bf16 head-scatter [bh][s][64] (Q scaled);
// V: f16 V^T [bh][d][s] via LDS-transpose.
// ---------------------------------------------------------------------------
__global__ __launch_bounds__(256) void gemm_qkv(
    const u16* __restrict__ A, const u16* __restrict__ Wbase,
    const float* __restrict__ bq, const float* __restrict__ bk,
    const float* __restrict__ bv,
    u16* __restrict__ q_out, u16* __restrict__ k_out, u16* __restrict__ v_out)
{
  __shared__ __attribute__((aligned(16))) u16 smem[8704];
  u16* As = smem;          // 128x32 linear: chunk c=(r*4+cc) at &As[c*8]
  u16* Bs = smem + 4096;   // 64x32 linear

  const int tid = threadIdx.x;
  const int w = tid >> 6, lane = tid & 63, lo = lane & 15, quad = lane >> 4;
  const int bm = blockIdx.x & 63, bn = blockIdx.x >> 6;
  const int mat = bn / 12;                 // 0=Q, 1=K, 2=V
  const int n0 = (bn - mat * 12) * 64;     // col offset within matrix
  const int m0 = bm * 128;
  const u16* W = Wbase + (size_t)mat * W_ELEMS;
  const float* bias = mat == 0 ? bq : (mat == 1 ? bk : bv);
  const float scale = mat == 0 ? ATT_SCALE : 1.0f;

  // per-thread global source offsets (k0-invariant)
  size_t aoff[2];
#pragma unroll
  for (int it = 0; it < 2; ++it) {
    int c = tid + it * 256, r = c >> 2, ccl = c & 3;
    int ccg = ccl ^ ((r >> 1) & 3);
    aoff[it] = (size_t)(m0 + r) * DIM + ccg * 8;
  }
  size_t boff;
  {
    int r = tid >> 2, ccl = tid & 3;
    int ccg = ccl ^ ((r >> 1) & 3);
    boff = (size_t)(n0 + r) * DIM + ccg * 8;
  }

  floatx4 acc[2][4];
#pragma unroll
  for (int mi = 0; mi < 2; mi++)
#pragma unroll
    for (int ni = 0; ni < 4; ni++) acc[mi][ni] = (floatx4){0.f, 0.f, 0.f, 0.f};

  for (int k0 = 0; k0 < DIM; k0 += 32) {
    __syncthreads();                      // all waves done reading prev tile
#pragma unroll
    for (int it = 0; it < 2; ++it)
      gld_lds16(&A[aoff[it] + k0], &As[(it * 256 + w * 64) * 8]);
    gld_lds16(&W[boff + k0], &Bs[(w * 64) * 8]);
    __syncthreads();                      // vmcnt(0) drain -> LDS visible

    bf16x8 af[2], bfr[4];
#pragma unroll
    for (int mi = 0; mi < 2; mi++) {
      int row = w * 32 + mi * 16 + lo;
      int s = quad ^ ((row >> 1) & 3);
      af[mi] = *(const bf16x8*)&As[row * 32 + s * 8];
    }
#pragma unroll
    for (int ni = 0; ni < 4; ni++) {
      int row = ni * 16 + lo;
      int s = quad ^ ((row >> 1) & 3);
      bfr[ni] = *(const bf16x8*)&Bs[row * 32 + s * 8];
    }
#pragma unroll
    for (int mi = 0; mi < 2; mi++)
#pragma unroll
      for (int ni = 0; ni < 4; ni++)
        acc[mi][ni] = __builtin_amdgcn_mfma_f32_16x16x32_bf16(af[mi], bfr[ni], acc[mi][ni], 0, 0, 0);
  }

  if (mat == 2) {
    __syncthreads();   // T overlays As/Bs still being read by other waves
    u16 (*T)[136] = (u16(*)[136])smem;
#pragma unroll
    for (int mi = 0; mi < 2; mi++)
#pragma unroll
      for (int ni = 0; ni < 4; ni++) {
        int col = ni * 16 + lo;
        float bb = bias[n0 + col];
        float v0 = acc[mi][ni][0] + bb, v1 = acc[mi][ni][1] + bb;
        float v2 = acc[mi][ni][2] + bb, v3 = acc[mi][ni][3] + bb;
        *(uint2*)&T[col][w * 32 + mi * 16 + quad * 4] =
            make_uint2(pkrtz2(v0, v1), pkrtz2(v2, v3));
      }
    __syncthreads();
    const int b = m0 >> 11, s0 = m0 & 2047;
#pragma unroll
    for (int it = 0; it < 4; ++it) {
      int ch = tid + it * 256;
      int col = ch >> 4, sc = ch & 15;
      int gcol = n0 + col;
      int h = gcol / HD, d = gcol - h * HD;
      size_t dst = ((size_t)(b * NH + h) * HDP + d) * S_LEN + s0 + sc * 8;
      *(uint4*)&v_out[dst] = *(const uint4*)&T[col][sc * 8];
    }
    return;
  }

  u16* out = mat == 0 ? q_out : k_out;
#pragma unroll
  for (int mi = 0; mi < 2; mi++)
#pragma unroll
    for (int ni = 0; ni < 4; ni++)
#pragma unroll
      for (int r = 0; r < 4; r++) {
        int row = m0 + w * 32 + mi * 16 + quad * 4 + r;
        int col = n0 + ni * 16 + lo;
        float v = (acc[mi][ni][r] + bias[col]) * scale;
        int b = row >> 11, s = row & 2047;
        int h = col / HD, d = col - h * HD;
        out[((size_t)((b * NH + h) * S_LEN + s)) * HDP + d] = f2b(v);
      }
}

// ---------------------------------------------------------------------------
// Wo GEMM: A = attn out HEAD-MAJOR [bh][s][48] bf16; out fp32 [8192][768].
// grid 768. Same global_load_lds staging; A source col is the SWIZZLED col
// (h,d derived from ccg), 16B-aligned (48%8==0, 96=6*16).
// ---------------------------------------------------------------------------
__global__ __launch_bounds__(256) void gemm_wo(
    const u16* __restrict__ A, const u16* __restrict__ W,
    const float* __restrict__ bias, float* __restrict__ out)
{
  __shared__ __attribute__((aligned(16))) u16 smem[6144];
  u16* As = smem;
  u16* Bs = smem + 4096;

  const int tid = threadIdx.x;
  const int w = tid >> 6, lane = tid & 63, lo = lane & 15, quad = lane >> 4;
  const int bm = blockIdx.x & 63, bn = blockIdx.x >> 6;
  const int m0 = bm * 128, n0 = bn * 64;

  // per-thread A chunk coords (row fixed; col = k0 + ccg*8 varies)
  int ar[2], accg[2];
#pragma unroll
  for (int it = 0; it < 2; ++it) {
    int c = tid + it * 256, r = c >> 2, ccl = c & 3;
    ar[it] = m0 + r;
    accg[it] = (ccl ^ ((r >> 1) & 3)) * 8;
  }
  size_t boff;
  {
    int r = tid >> 2, ccl = tid & 3;
    boff = (size_t)(n0 + r) * DIM + (ccl ^ ((r >> 1) & 3)) * 8;
  }

  floatx4 acc[2][4];
#pragma unroll
  for (int mi = 0; mi < 2; mi++)
#pragma unroll
    for (int ni = 0; ni < 4; ni++) acc[mi][ni] = (floatx4){0.f, 0.f, 0.f, 0.f};

  for (int k0 = 0; k0 < DIM; k0 += 32) {
    __syncthreads();
#pragma unroll
    for (int it = 0; it < 2; ++it) {
      int row = ar[it], c8 = k0 + accg[it];
      int h = c8 / HD, d = c8 - h * HD;
      int b = row >> 11, s = row & 2047;
      gld_lds16(&A[((size_t)((b * NH + h) * S_LEN + s)) * HD + d],
                &As[(it * 256 + w * 64) * 8]);
    }
    gld_lds16(&W[boff + k0], &Bs[(w * 64) * 8]);
    __syncthreads();

    bf16x8 af[2], bfr[4];
#pragma unroll
    for (int mi = 0; mi < 2; mi++) {
      int row = w * 32 + mi * 16 + lo;
      int s = quad ^ ((row >> 1) & 3);
      af[mi] = *(const bf16x8*)&As[row * 32 + s * 8];
    }
#pragma unroll
    for (int ni = 0; ni < 4; ni++) {
      int row = ni * 16 + lo;
      int s = quad ^ ((row >> 1) & 3);
      bfr[ni] = *(const bf16x8*)&Bs[row * 32 + s * 8];
    }
#pragma unroll
    for (int mi = 0; mi < 2; mi++)
#pragma unroll
      for (int ni = 0; ni < 4; ni++)
        acc[mi][ni] = __builtin_amdgcn_mfma_f32_16x16x32_bf16(af[mi], bfr[ni], acc[mi][ni], 0, 0, 0);
  }

#pragma unroll
  for (int mi = 0; mi < 2; mi++)
#pragma unroll
    for (int ni = 0; ni < 4; ni++)
#pragma unroll
      for (int r = 0; r < 4; r++) {
        int row = m0 + w * 32 + mi * 16 + quad * 4 + r;
        int col = n0 + ni * 16 + lo;
        out[(size_t)row * DIM + col] = acc[mi][ni][r] + bias[col];
      }
}

// ---------------------------------------------------------------------------
// Flash attention, 32x32x16 MFMA, swapped QK^T (mfma(K,Q) -> P[key][q=l31]).
// Round-5 verified structure + s_setprio(1) around MFMA clusters (T5, m191).
// ---------------------------------------------------------------------------
#define STG_LOAD(k0n) do {                                                     \
  _Pragma("unroll")                                                            \
  for (int it = 0; it < 3; ++it) {                                             \
    int c = tid + it * 256;                                                    \
    if (c < 384) {                                                             \
      int r = c / 6, cc = c - r * 6;                                           \
      stg[it] = *(const uint4*)&K[base + (size_t)((k0n) + r) * HDP + cc * 8];  \
    } else {                                                                   \
      int c2 = c - 384, r = c2 >> 3, cc = c2 & 7;                              \
      stg[it] = *(const uint4*)&V[base + (size_t)r * S_LEN + (k0n) + cc * 8];  \
    }                                                                          \
  }                                                                            \
} while (0)

#define STG_WRITE(bufi) do {                                                   \
  _Pragma("unroll")                                                            \
  for (int it = 0; it < 3; ++it) {                                             \
    int c = tid + it * 256;                                                    \
    if (c < 384) {                                                             \
      int r = c / 6, cc = c - r * 6;                                           \
      *(uint4*)&Ks[bufi][r][cc * 8] = stg[it];                                 \
    } else {                                                                   \
      int c2 = c - 384, r = c2 >> 3, cc = c2 & 7;                              \
      *(uint4*)&Vt[bufi][r][cc * 8] = stg[it];                                 \
    }                                                                          \
  }                                                                            \
} while (0)

__global__ __launch_bounds__(256, 2) void attn_kernel(
    const u16* __restrict__ Q, const u16* __restrict__ K,
    const u16* __restrict__ V, u16* __restrict__ O)
{
  __shared__ __attribute__((aligned(16))) u16 Ks[2][64][56];  // keys x d(<48)
  __shared__ __attribute__((aligned(16))) u16 Vt[2][64][72];  // d x keys (f16)

  const int tid = threadIdx.x;
  const int w = tid >> 6, lane = tid & 63, l31 = lane & 31, hi = lane >> 5;
  // XCD-locality swizzle: 512 flat blocks; all 8 q-blocks of a bh and 8
  // consecutive bh share one XCD (id%8 = XCD round-robin assumption).
  const int flat = blockIdx.x;
  const int xcd = flat & 7, sub = flat >> 3;          // sub in [0,64)
  const int bh = xcd * 8 + (sub >> 3);                // 8 bh per XCD
  const int q0 = (sub & 7) * 256;                     // 8 q-blocks per bh
  const size_t base = (size_t)bh * S_LEN * HDP;

  // Q fragments (B-operand of swapped QK): Q[q0+w*64+t*32+l31][ks*16+hi*8+j]
  bf16x8 qf[2][3];
#pragma unroll
  for (int t = 0; t < 2; t++)
#pragma unroll
    for (int ks = 0; ks < 3; ks++)
      qf[t][ks] = *(const bf16x8*)
          &Q[base + (size_t)(q0 + w * 64 + t * 32 + l31) * HDP + ks * 16 + hi * 8];

  floatx16 oacc[2][2];
#pragma unroll
  for (int t = 0; t < 2; t++)
#pragma unroll
    for (int nd = 0; nd < 2; nd++)
#pragma unroll
      for (int r = 0; r < 16; r++) oacc[t][nd][r] = 0.f;

  float l_lane[2] = {0.f, 0.f};   // f32 denom for q = l31 (this lane's key half)

  uint4 stg[3];
  STG_LOAD(0);
  STG_WRITE(0);

  for (int ti = 0; ti < 32; ++ti) {
    const int cur = ti & 1;
    if (ti < 31) STG_LOAD((ti + 1) * 64);   // in flight across the barrier (T14)
    __syncthreads();

    // K A-fragments, shared by both q-subtiles
    bf16x8 ak[2][3];
#pragma unroll
    for (int na = 0; na < 2; na++)
#pragma unroll
      for (int ks = 0; ks < 3; ks++)
        ak[na][ks] = *(const bf16x8*)&Ks[cur][na * 32 + l31][ks * 16 + hi * 8];

    // QK^T (swapped) + exp + pack; pk[t][na][m] covers keys
    // na*32 + 8*(m>>1) + 4*hi + 2*(m&1) + {0,1}, all for q = l31.
    u32 pk[2][2][8];
#pragma unroll
    for (int t = 0; t < 2; t++) {
      floatx16 s0, s1;
#pragma unroll
      for (int r = 0; r < 16; r++) { s0[r] = 0.f; s1[r] = 0.f; }
      __builtin_amdgcn_s_setprio(1);
#pragma unroll
      for (int ks = 0; ks < 3; ks++) {
        s0 = __builtin_amdgcn_mfma_f32_32x32x16_bf16(ak[0][ks], qf[t][ks], s0, 0, 0, 0);
        s1 = __builtin_amdgcn_mfma_f32_32x32x16_bf16(ak[1][ks], qf[t][ks], s1, 0, 0, 0);
      }
      __builtin_amdgcn_s_setprio(0);
#pragma unroll
      for (int m = 0; m < 8; m++) {
        float a0 = __expf(s0[2 * m]), a1 = __expf(s0[2 * m + 1]);
        float b0 = __expf(s1[2 * m]), b1 = __expf(s1[2 * m + 1]);
        l_lane[t] += (a0 + a1) + (b0 + b1);
        pk[t][0][m] = pkrtz2(a0, a1);
        pk[t][1][m] = pkrtz2(b0, b1);
      }
    }

    // O += P @ V : A-frag rebuilt in registers via permlane32_swap
#pragma unroll
    for (int kt = 0; kt < 4; kt++) {
      f16x8 bv0 = *(const f16x8*)&Vt[cur][l31][kt * 16 + hi * 8];
      f16x8 bv1 = *(const f16x8*)&Vt[cur][32 + l31][kt * 16 + hi * 8];
      const int na = kt >> 1, k4 = (kt & 1) * 4;
#pragma unroll
      for (int t = 0; t < 2; t++) {
        u32 w0 = pk[t][na][k4 + 0], w2 = pk[t][na][k4 + 2];
        u32 w1 = pk[t][na][k4 + 1], w3 = pk[t][na][k4 + 3];
        pl32swap(w0, w2);
        pl32swap(w1, w3);
        union { u32 u[4]; f16x8 f; } af;
        af.u[0] = w0; af.u[1] = w1; af.u[2] = w2; af.u[3] = w3;
        __builtin_amdgcn_s_setprio(1);
        oacc[t][0] = __builtin_amdgcn_mfma_f32_32x32x16_f16(af.f, bv0, oacc[t][0], 0, 0, 0);
        oacc[t][1] = __builtin_amdgcn_mfma_f32_32x32x16_f16(af.f, bv1, oacc[t][1], 0, 0, 0);
        __builtin_amdgcn_s_setprio(0);
      }
    }

    if (ti < 31) STG_WRITE(cur ^ 1);   // write-late into the other buffer
  }

  // epilogue: complete l(q=l31) across halves, fetch per-output-row denom via
  // __shfl from lane q_local, write HEAD-MAJOR O[bh][q][48] (contiguous 96B
  // rows, block-private -> full-line writes on one XCD).
  const size_t obase = (size_t)bh * S_LEN * HD;
  float lt_full[2];
#pragma unroll
  for (int t = 0; t < 2; t++)
    lt_full[t] = l_lane[t] + __shfl_xor(l_lane[t], 32);
#pragma unroll
  for (int t = 0; t < 2; t++) {
#pragma unroll
    for (int r = 0; r < 16; r++) {
      int q_local = (r & 3) + 8 * (r >> 2) + 4 * hi;
      float l_r = __shfl(lt_full[t], q_local);
      float inv = 1.f / l_r;
      int q = q0 + w * 64 + t * 32 + q_local;
      u16* orow = O + obase + (size_t)q * HD;
      orow[l31] = f2b(oacc[t][0][r] * inv);
      if (l31 < 16) orow[32 + l31] = f2b(oacc[t][1][r] * inv);
    }
  }
}

// ---------------------------------------------------------------------------
extern "C" void kernel_launch(void* const* d_in, const int* in_sizes, int n_in,
                              void* d_out, int out_size, void* d_ws, size_t ws_size,
                              hipStream_t stream)
{
  const float* x  = (const float*)d_in[0];
  const float* Wq = (const float*)d_in[1];
  const float* bq = (const float*)d_in[2];
  const float* Wk = (const float*)d_in[3];
  const float* bk = (const float*)d_in[4];
  const float* Wv = (const float*)d_in[5];
  const float* bv = (const float*)d_in[6];
  const float* Wo = (const float*)d_in[7];
  const float* bo = (const float*)d_in[8];

  u16* ws   = (u16*)d_ws;
  const size_t qkv_elems = (size_t)BHEADS * S_LEN * HDP;  // 8.39M u16 each
  u16* q_ws = ws;                                         // [bh][s][64] bf16
  u16* k_ws = q_ws + qkv_elems;                           // [bh][s][64] bf16
  u16* v_ws = k_ws + qkv_elems;                           // [bh][d][s]  f16 (V^T)
  u16* x_bf = v_ws + qkv_elems;                           // [8192][768] bf16
  u16* a_ws = x_bf;   // aliased: attn writes [bh][s][48] (6.29M u16 = x_bf size)
  u16* w_bf = x_bf + (size_t)8192 * DIM;                  // 4x[768][768] bf16
  u16* wo_bf = w_bf + (size_t)3 * W_ELEMS;

  cvt_all<<<dim3(4224), dim3(256), 0, stream>>>(x, Wq, Wk, Wv, Wo, x_bf, w_bf);
  gemm_qkv<<<dim3(2304), dim3(256), 0, stream>>>(x_bf, w_bf, bq, bk, bv,
                                                 q_ws, k_ws, v_ws);
  attn_kernel<<<dim3(512), dim3(256), 0, stream>>>(q_ws, k_ws, v_ws, a_ws);
  gemm_wo<<<dim3(768), dim3(256), 0, stream>>>(a_ws, wo_bf, bo, (float*)d_out);
}

// Round 9
// 257.625 us; speedup vs baseline: 1.4635x; 1.0258x over previous
//
#include <hip/hip_runtime.h>

typedef __bf16 bf16_t;
typedef bf16_t bf16x8 __attribute__((ext_vector_type(8)));
typedef _Float16 f16_t;
typedef __fp16 hf16x2 __attribute__((ext_vector_type(2)));   // cvt_pkrtz return type
typedef f16_t f16x8 __attribute__((ext_vector_type(8)));
typedef float floatx4 __attribute__((ext_vector_type(4)));
typedef float floatx16 __attribute__((ext_vector_type(16)));

#define S_LEN 2048
#define DIM 768
#define NH 16
#define HD 48
#define HDP 64
#define BHEADS 64          // B * NH
#define ATT_SCALE 0.14433756729740643f  // 1/sqrt(48)
#define W_ELEMS (DIM * DIM)

typedef unsigned short u16;
typedef unsigned int u32;

__device__ __forceinline__ u16 f2b(float f) {
  union { float f; u32 i; } z; z.f = f;
  u32 i = z.i;
  return (u16)((i + 0x7fffu + ((i >> 16) & 1u)) >> 16);  // RNE
}
__device__ __forceinline__ u32 pack2(float a, float b) {
  return (u32)f2b(a) | ((u32)f2b(b) << 16);
}
__device__ __forceinline__ u32 pkrtz2(float a, float b) {   // 2x f32 -> packed f16
  union { hf16x2 h; u32 u; } z;
  z.h = __builtin_amdgcn_cvt_pkrtz(a, b);
  return z.u;
}
// v_permlane32_swap_b32: a' = [a.lanes0-31, b.lanes0-31]; b' = [a.lanes32-63, b.lanes32-63]
__device__ __forceinline__ void pl32swap(u32& a, u32& b) {
  asm("v_permlane32_swap_b32 %0, %1" : "+v"(a), "+v"(b));
}
// async global->LDS DMA, 16B per lane. LDS dest is wave-uniform base + lane*16;
// global src is per-lane. vmcnt-counted; __syncthreads() drains it.
__device__ __forceinline__ void gld_lds16(const void* g, void* l) {
  __builtin_amdgcn_global_load_lds(
      (const __attribute__((address_space(1))) u32*)g,
      (__attribute__((address_space(3))) u32*)l, 16, 0, 0);
}

// ---------------------------------------------------------------------------
// Fused fp32 -> bf16 convert for x (blocks 0..3071) and the 4 weight
// matrices (blocks 3072..4223, 288 per matrix). One launch instead of two.
// ---------------------------------------------------------------------------
__global__ __launch_bounds__(256) void cvt_all(
    const float* __restrict__ x,
    const float* __restrict__ w0, const float* __restrict__ w1,
    const float* __restrict__ w2, const float* __restrict__ w3,
    u16* __restrict__ x_dst, u16* __restrict__ w_dst)
{
  const int blk = blockIdx.x;
  const float* src;
  u16* dst;
  int idx;
  if (blk < 3072) {
    src = x; dst = x_dst; idx = blk * 256 + threadIdx.x;
  } else {
    int wb = blk - 3072;
    int j = wb / 288;
    src = (j == 0) ? w0 : (j == 1) ? w1 : (j == 2) ? w2 : w3;
    dst = w_dst + (size_t)j * W_ELEMS;
    idx = (wb - j * 288) * 256 + threadIdx.x;
  }
  const float4* s = (const float4*)src;
  float4 a = s[idx * 2], b = s[idx * 2 + 1];
  *(uint4*)&dst[(size_t)idx * 8] =
      make_uint4(pack2(a.x, a.y), pack2(a.z, a.w), pack2(b.x, b.y), pack2(b.z, b.w));
}

// ===========================================================================
// GEMM staging via global_load_lds: LINEAR LDS, source-side column XOR
// swizzle ccg = ccl ^ ((r>>1)&3) with the same XOR on the read side
// (rule 21) -> conflict-free reads, coalescing preserved (XOR permutes
// lanes within one 64B line). 2 barriers per K-step (m97 structure).
// ===========================================================================

// ---------------------------------------------------------------------------
// Fused QKV GEMM, 128x128 tile (m97 rung: 4x4 frags/wave -> 8 ds_read_b128
// per 16 MFMA, balanced pipes). grid 1152 = 64 m x 18 n; mat = bn/6
// (0=Q,1=K,2=V), n0 = (bn%6)*128. Q/K: bf16 head-scatter [bh][s][64]
// (Q scaled); V: f16 V^T [bh][d][s] via two-pass 64-col LDS transpose.
// LDS: As 128x32 + Bs 128x32 = 8192 u16 = T overlay 64x136 = 8704 u16.
// ---------------------------------------------------------------------------
__global__ __launch_bounds__(256) void gemm_qkv(
    const u16* __restrict__ A, const u16* __restrict__ Wbase,
    const float* __restrict__ bq, const float* __restrict__ bk,
    const float* __restrict__ bv,
    u16* __restrict__ q_out, u16* __restrict__ k_out, u16* __restrict__ v_out)
{
  __shared__ __attribute__((aligned(16))) u16 smem[8704];
  u16* As = smem;          // 128x32 linear: chunk c=(r*4+cc) at &As[c*8]
  u16* Bs = smem + 4096;   // 128x32 linear

  const int tid = threadIdx.x;
  const int w = tid >> 6, lane = tid & 63, lo = lane & 15, quad = lane >> 4;
  const int wr = w >> 1, wc = w & 1;
  const int bm = blockIdx.x & 63, bn = blockIdx.x >> 6;
  const int mat = bn / 6;                  // 0=Q, 1=K, 2=V
  const int n0 = (bn - mat * 6) * 128;     // col offset within matrix
  const int m0 = bm * 128;
  const u16* W = Wbase + (size_t)mat * W_ELEMS;
  const float* bias = mat == 0 ? bq : (mat == 1 ? bk : bv);
  const float scale = mat == 0 ? ATT_SCALE : 1.0f;

  // per-thread global source offsets (k0-invariant), source-side swizzle
  size_t aoff[2], boff[2];
#pragma unroll
  for (int it = 0; it < 2; ++it) {
    int c = tid + it * 256, r = c >> 2, ccl = c & 3;
    int ccg = ccl ^ ((r >> 1) & 3);
    aoff[it] = (size_t)(m0 + r) * DIM + ccg * 8;
    boff[it] = (size_t)(n0 + r) * DIM + ccg * 8;
  }

  floatx4 acc[4][4];
#pragma unroll
  for (int mi = 0; mi < 4; mi++)
#pragma unroll
    for (int ni = 0; ni < 4; ni++) acc[mi][ni] = (floatx4){0.f, 0.f, 0.f, 0.f};

  for (int k0 = 0; k0 < DIM; k0 += 32) {
    __syncthreads();                      // all waves done reading prev tile
#pragma unroll
    for (int it = 0; it < 2; ++it) {
      gld_lds16(&A[aoff[it] + k0], &As[(it * 256 + w * 64) * 8]);
      gld_lds16(&W[boff[it] + k0], &Bs[(it * 256 + w * 64) * 8]);
    }
    __syncthreads();                      // vmcnt(0) drain -> LDS visible

    bf16x8 af[4], bfr[4];
#pragma unroll
    for (int mi = 0; mi < 4; mi++) {
      int row = wr * 64 + mi * 16 + lo;
      int s = quad ^ ((row >> 1) & 3);
      af[mi] = *(const bf16x8*)&As[row * 32 + s * 8];
    }
#pragma unroll
    for (int ni = 0; ni < 4; ni++) {
      int row = wc * 64 + ni * 16 + lo;
      int s = quad ^ ((row >> 1) & 3);
      bfr[ni] = *(const bf16x8*)&Bs[row * 32 + s * 8];
    }
#pragma unroll
    for (int mi = 0; mi < 4; mi++)
#pragma unroll
      for (int ni = 0; ni < 4; ni++)
        acc[mi][ni] = __builtin_amdgcn_mfma_f32_16x16x32_bf16(af[mi], bfr[ni], acc[mi][ni], 0, 0, 0);
  }

  if (mat == 2) {
    // V^T epilogue in two 64-col passes (T overlays staging: 64x136 u16)
    u16 (*T)[136] = (u16(*)[136])smem;
    const int b = m0 >> 11, s0 = m0 & 2047;
#pragma unroll
    for (int half = 0; half < 2; ++half) {
      __syncthreads();   // pass 0: staging reads done; pass 1: prev copy done
      if (wc == half) {
#pragma unroll
        for (int mi = 0; mi < 4; mi++)
#pragma unroll
          for (int ni = 0; ni < 4; ni++) {
            int colL = ni * 16 + lo;
            float bb = bias[n0 + half * 64 + colL];
            float v0 = acc[mi][ni][0] + bb, v1 = acc[mi][ni][1] + bb;
            float v2 = acc[mi][ni][2] + bb, v3 = acc[mi][ni][3] + bb;
            *(uint2*)&T[colL][wr * 64 + mi * 16 + quad * 4] =
                make_uint2(pkrtz2(v0, v1), pkrtz2(v2, v3));
          }
      }
      __syncthreads();
#pragma unroll
      for (int it = 0; it < 4; ++it) {
        int ch = tid + it * 256;
        int col = ch >> 4, sc = ch & 15;
        int gcol = n0 + half * 64 + col;
        int h = gcol / HD, d = gcol - h * HD;
        size_t dst = ((size_t)(b * NH + h) * HDP + d) * S_LEN + s0 + sc * 8;
        *(uint4*)&v_out[dst] = *(const uint4*)&T[col][sc * 8];
      }
    }
    return;
  }

  u16* out = mat == 0 ? q_out : k_out;
#pragma unroll
  for (int mi = 0; mi < 4; mi++)
#pragma unroll
    for (int ni = 0; ni < 4; ni++)
#pragma unroll
      for (int r = 0; r < 4; r++) {
        int row = m0 + wr * 64 + mi * 16 + quad * 4 + r;
        int col = n0 + wc * 64 + ni * 16 + lo;
        float v = (acc[mi][ni][r] + bias[col]) * scale;
        int b = row >> 11, s = row & 2047;
        int h = col / HD, d = col - h * HD;
        out[((size_t)((b * NH + h) * S_LEN + s)) * HDP + d] = f2b(v);
      }
}

// ---------------------------------------------------------------------------
// Wo GEMM (round-8 verified): A = attn out HEAD-MAJOR [bh][s][48] bf16;
// out fp32 [8192][768]. Tile 128x64, grid 768, gld_lds staging.
// ---------------------------------------------------------------------------
__global__ __launch_bounds__(256) void gemm_wo(
    const u16* __restrict__ A, const u16* __restrict__ W,
    const float* __restrict__ bias, float* __restrict__ out)
{
  __shared__ __attribute__((aligned(16))) u16 smem[6144];
  u16* As = smem;
  u16* Bs = smem + 4096;

  const int tid = threadIdx.x;
  const int w = tid >> 6, lane = tid & 63, lo = lane & 15, quad = lane >> 4;
  const int bm = blockIdx.x & 63, bn = blockIdx.x >> 6;
  const int m0 = bm * 128, n0 = bn * 64;

  // per-thread A chunk coords (row fixed; col = k0 + ccg*8 varies)
  int ar[2], accg[2];
#pragma unroll
  for (int it = 0; it < 2; ++it) {
    int c = tid + it * 256, r = c >> 2, ccl = c & 3;
    ar[it] = m0 + r;
    accg[it] = (ccl ^ ((r >> 1) & 3)) * 8;
  }
  size_t boff;
  {
    int r = tid >> 2, ccl = tid & 3;
    boff = (size_t)(n0 + r) * DIM + (ccl ^ ((r >> 1) & 3)) * 8;
  }

  floatx4 acc[2][4];
#pragma unroll
  for (int mi = 0; mi < 2; mi++)
#pragma unroll
    for (int ni = 0; ni < 4; ni++) acc[mi][ni] = (floatx4){0.f, 0.f, 0.f, 0.f};

  for (int k0 = 0; k0 < DIM; k0 += 32) {
    __syncthreads();
#pragma unroll
    for (int it = 0; it < 2; ++it) {
      int row = ar[it], c8 = k0 + accg[it];
      int h = c8 / HD, d = c8 - h * HD;
      int b = row >> 11, s = row & 2047;
      gld_lds16(&A[((size_t)((b * NH + h) * S_LEN + s)) * HD + d],
                &As[(it * 256 + w * 64) * 8]);
    }
    gld_lds16(&W[boff + k0], &Bs[(w * 64) * 8]);
    __syncthreads();

    bf16x8 af[2], bfr[4];
#pragma unroll
    for (int mi = 0; mi < 2; mi++) {
      int row = w * 32 + mi * 16 + lo;
      int s = quad ^ ((row >> 1) & 3);
      af[mi] = *(const bf16x8*)&As[row * 32 + s * 8];
    }
#pragma unroll
    for (int ni = 0; ni < 4; ni++) {
      int row = ni * 16 + lo;
      int s = quad ^ ((row >> 1) & 3);
      bfr[ni] = *(const bf16x8*)&Bs[row * 32 + s * 8];
    }
#pragma unroll
    for (int mi = 0; mi < 2; mi++)
#pragma unroll
      for (int ni = 0; ni < 4; ni++)
        acc[mi][ni] = __builtin_amdgcn_mfma_f32_16x16x32_bf16(af[mi], bfr[ni], acc[mi][ni], 0, 0, 0);
  }

#pragma unroll
  for (int mi = 0; mi < 2; mi++)
#pragma unroll
    for (int ni = 0; ni < 4; ni++)
#pragma unroll
      for (int r = 0; r < 4; r++) {
        int row = m0 + w * 32 + mi * 16 + quad * 4 + r;
        int col = n0 + ni * 16 + lo;
        out[(size_t)row * DIM + col] = acc[mi][ni][r] + bias[col];
      }
}

// ---------------------------------------------------------------------------
// Flash attention, 32x32x16 MFMA, swapped QK^T (mfma(K,Q) -> P[key][q=l31]).
// Round-7 verified body (112.2 us). setprio REVERTED: measured -3.6% (round
// 8) -- our lockstep 4-wave loop is the m190 null regime, not m191's.
// ---------------------------------------------------------------------------
#define STG_LOAD(k0n) do {                                                     \
  _Pragma("unroll")                                                            \
  for (int it = 0; it < 3; ++it) {                                             \
    int c = tid + it * 256;                                                    \
    if (c < 384) {                                                             \
      int r = c / 6, cc = c - r * 6;                                           \
      stg[it] = *(const uint4*)&K[base + (size_t)((k0n) + r) * HDP + cc * 8];  \
    } else {                                                                   \
      int c2 = c - 384, r = c2 >> 3, cc = c2 & 7;                              \
      stg[it] = *(const uint4*)&V[base + (size_t)r * S_LEN + (k0n) + cc * 8];  \
    }                                                                          \
  }                                                                            \
} while (0)

#define STG_WRITE(bufi) do {                                                   \
  _Pragma("unroll")                                                            \
  for (int it = 0; it < 3; ++it) {                                             \
    int c = tid + it * 256;                                                    \
    if (c < 384) {                                                             \
      int r = c / 6, cc = c - r * 6;                                           \
      *(uint4*)&Ks[bufi][r][cc * 8] = stg[it];                                 \
    } else {                                                                   \
      int c2 = c - 384, r = c2 >> 3, cc = c2 & 7;                              \
      *(uint4*)&Vt[bufi][r][cc * 8] = stg[it];                                 \
    }                                                                          \
  }                                                                            \
} while (0)

__global__ __launch_bounds__(256, 2) void attn_kernel(
    const u16* __restrict__ Q, const u16* __restrict__ K,
    const u16* __restrict__ V, u16* __restrict__ O)
{
  __shared__ __attribute__((aligned(16))) u16 Ks[2][64][56];  // keys x d(<48)
  __shared__ __attribute__((aligned(16))) u16 Vt[2][64][72];  // d x keys (f16)

  const int tid = threadIdx.x;
  const int w = tid >> 6, lane = tid & 63, l31 = lane & 31, hi = lane >> 5;
  // XCD-locality swizzle: 512 flat blocks; all 8 q-blocks of a bh and 8
  // consecutive bh share one XCD (id%8 = XCD round-robin assumption).
  const int flat = blockIdx.x;
  const int xcd = flat & 7, sub = flat >> 3;          // sub in [0,64)
  const int bh = xcd * 8 + (sub >> 3);                // 8 bh per XCD
  const int q0 = (sub & 7) * 256;                     // 8 q-blocks per bh
  const size_t base = (size_t)bh * S_LEN * HDP;

  // Q fragments (B-operand of swapped QK): Q[q0+w*64+t*32+l31][ks*16+hi*8+j]
  bf16x8 qf[2][3];
#pragma unroll
  for (int t = 0; t < 2; t++)
#pragma unroll
    for (int ks = 0; ks < 3; ks++)
      qf[t][ks] = *(const bf16x8*)
          &Q[base + (size_t)(q0 + w * 64 + t * 32 + l31) * HDP + ks * 16 + hi * 8];

  floatx16 oacc[2][2];
#pragma unroll
  for (int t = 0; t < 2; t++)
#pragma unroll
    for (int nd = 0; nd < 2; nd++)
#pragma unroll
      for (int r = 0; r < 16; r++) oacc[t][nd][r] = 0.f;

  float l_lane[2] = {0.f, 0.f};   // f32 denom for q = l31 (this lane's key half)

  uint4 stg[3];
  STG_LOAD(0);
  STG_WRITE(0);

  for (int ti = 0; ti < 32; ++ti) {
    const int cur = ti & 1;
    if (ti < 31) STG_LOAD((ti + 1) * 64);   // in flight across the barrier (T14)
    __syncthreads();

    // K A-fragments, shared by both q-subtiles
    bf16x8 ak[2][3];
#pragma unroll
    for (int na = 0; na < 2; na++)
#pragma unroll
      for (int ks = 0; ks < 3; ks++)
        ak[na][ks] = *(const bf16x8*)&Ks[cur][na * 32 + l31][ks * 16 + hi * 8];

    // QK^T (swapped) + exp + pack; pk[t][na][m] covers keys
    // na*32 + 8*(m>>1) + 4*hi + 2*(m&1) + {0,1}, all for q = l31.
    u32 pk[2][2][8];
#pragma unroll
    for (int t = 0; t < 2; t++) {
      floatx16 s0, s1;
#pragma unroll
      for (int r = 0; r < 16; r++) { s0[r] = 0.f; s1[r] = 0.f; }
#pragma unroll
      for (int ks = 0; ks < 3; ks++) {
        s0 = __builtin_amdgcn_mfma_f32_32x32x16_bf16(ak[0][ks], qf[t][ks], s0, 0, 0, 0);
        s1 = __builtin_amdgcn_mfma_f32_32x32x16_bf16(ak[1][ks], qf[t][ks], s1, 0, 0, 0);
      }
#pragma unroll
      for (int m = 0; m < 8; m++) {
        float a0 = __expf(s0[2 * m]), a1 = __expf(s0[2 * m + 1]);
        float b0 = __expf(s1[2 * m]), b1 = __expf(s1[2 * m + 1]);
        l_lane[t] += (a0 + a1) + (b0 + b1);
        pk[t][0][m] = pkrtz2(a0, a1);
        pk[t][1][m] = pkrtz2(b0, b1);
      }
    }

    // O += P @ V : A-frag rebuilt in registers via permlane32_swap
#pragma unroll
    for (int kt = 0; kt < 4; kt++) {
      f16x8 bv0 = *(const f16x8*)&Vt[cur][l31][kt * 16 + hi * 8];
      f16x8 bv1 = *(const f16x8*)&Vt[cur][32 + l31][kt * 16 + hi * 8];
      const int na = kt >> 1, k4 = (kt & 1) * 4;
#pragma unroll
      for (int t = 0; t < 2; t++) {
        u32 w0 = pk[t][na][k4 + 0], w2 = pk[t][na][k4 + 2];
        u32 w1 = pk[t][na][k4 + 1], w3 = pk[t][na][k4 + 3];
        pl32swap(w0, w2);
        pl32swap(w1, w3);
        union { u32 u[4]; f16x8 f; } af;
        af.u[0] = w0; af.u[1] = w1; af.u[2] = w2; af.u[3] = w3;
        oacc[t][0] = __builtin_amdgcn_mfma_f32_32x32x16_f16(af.f, bv0, oacc[t][0], 0, 0, 0);
        oacc[t][1] = __builtin_amdgcn_mfma_f32_32x32x16_f16(af.f, bv1, oacc[t][1], 0, 0, 0);
      }
    }

    if (ti < 31) STG_WRITE(cur ^ 1);   // write-late into the other buffer
  }

  // epilogue: complete l(q=l31) across halves, fetch per-output-row denom via
  // __shfl from lane q_local, write HEAD-MAJOR O[bh][q][48] (contiguous 96B
  // rows, block-private -> full-line writes on one XCD).
  const size_t obase = (size_t)bh * S_LEN * HD;
  float lt_full[2];
#pragma unroll
  for (int t = 0; t < 2; t++)
    lt_full[t] = l_lane[t] + __shfl_xor(l_lane[t], 32);
#pragma unroll
  for (int t = 0; t < 2; t++) {
#pragma unroll
    for (int r = 0; r < 16; r++) {
      int q_local = (r & 3) + 8 * (r >> 2) + 4 * hi;
      float l_r = __shfl(lt_full[t], q_local);
      float inv = 1.f / l_r;
      int q = q0 + w * 64 + t * 32 + q_local;
      u16* orow = O + obase + (size_t)q * HD;
      orow[l31] = f2b(oacc[t][0][r] * inv);
      if (l31 < 16) orow[32 + l31] = f2b(oacc[t][1][r] * inv);
    }
  }
}

// ---------------------------------------------------------------------------
extern "C" void kernel_launch(void* const* d_in, const int* in_sizes, int n_in,
                              void* d_out, int out_size, void* d_ws, size_t ws_size,
                              hipStream_t stream)
{
  const float* x  = (const float*)d_in[0];
  const float* Wq = (const float*)d_in[1];
  const float* bq = (const float*)d_in[2];
  const float* Wk = (const float*)d_in[3];
  const float* bk = (const float*)d_in[4];
  const float* Wv = (const float*)d_in[5];
  const float* bv = (const float*)d_in[6];
  const float* Wo = (const float*)d_in[7];
  const float* bo = (const float*)d_in[8];

  u16* ws   = (u16*)d_ws;
  const size_t qkv_elems = (size_t)BHEADS * S_LEN * HDP;  // 8.39M u16 each
  u16* q_ws = ws;                                         // [bh][s][64] bf16
  u16* k_ws = q_ws + qkv_elems;                           // [bh][s][64] bf16
  u16* v_ws = k_ws + qkv_elems;                           // [bh][d][s]  f16 (V^T)
  u16* x_bf = v_ws + qkv_elems;                           // [8192][768] bf16
  u16* a_ws = x_bf;   // aliased: attn writes [bh][s][48] (6.29M u16 = x_bf size)
  u16* w_bf = x_bf + (size_t)8192 * DIM;                  // 4x[768][768] bf16
  u16* wo_bf = w_bf + (size_t)3 * W_ELEMS;

  cvt_all<<<dim3(4224), dim3(256), 0, stream>>>(x, Wq, Wk, Wv, Wo, x_bf, w_bf);
  gemm_qkv<<<dim3(1152), dim3(256), 0, stream>>>(x_bf, w_bf, bq, bk, bv,
                                                 q_ws, k_ws, v_ws);
  attn_kernel<<<dim3(512), dim3(256), 0, stream>>>(q_ws, k_ws, v_ws, a_ws);
  gemm_wo<<<dim3(768), dim3(256), 0, stream>>>(a_ws, wo_bf, bo, (float*)d_out);
}